// Round 1
// baseline (124.219 us; speedup 1.0000x reference)
//
#include <hip/hip_runtime.h>

#define DD 128  // feature dim

// ---------------------------------------------------------------------------
// Stage 1: per-block partial Gram tiles  A = X^T X, B = Y^T Y  (each 128x128)
// Grid = 2*P blocks: [0,P) -> X slab -> apart[p], [P,2P) -> Y slab -> bpart[p].
// Block = 256 threads as 16x16; each thread owns an 8x8 tile of the 128x128
// output (64 fp32 accumulators in VGPRs). Rows staged through LDS in chunks
// of 8 (4 KB), with a register prefetch of the next chunk to hide HBM latency.
// X-blocks additionally accumulate diag sums s1 = sum <x_i,y_i>,
// s2 = sum <x_i,y_i>^2 (double atomics, ~8 per block).
// ---------------------------------------------------------------------------
__global__ __launch_bounds__(256)
void gram_kernel(const float* __restrict__ x, const float* __restrict__ y,
                 float* __restrict__ apart, float* __restrict__ bpart,
                 double* __restrict__ sc, int N, int P)
{
  const int blk = blockIdx.x;
  const bool isX = blk < P;
  const int p = isX ? blk : blk - P;
  const float* __restrict__ src = isX ? x : y;
  const int slab = N / P;
  const int row0 = p * slab;

  __shared__ float sh[8 * DD];  // 8 rows x 128 floats = 4 KB

  const int tid = threadIdx.x;
  const int tx = tid & 15, ty = tid >> 4;
  const int a0 = ty * 8, b0 = tx * 8;

  float acc[8][8];
#pragma unroll
  for (int i = 0; i < 8; ++i)
#pragma unroll
    for (int j = 0; j < 8; ++j) acc[i][j] = 0.f;

  const float4* gbase = (const float4*)(src + (size_t)row0 * DD);
  const int nchunks = slab / 8;  // chunk = 8 rows = 1024 floats = 256 float4
  float4 v = gbase[tid];
  for (int c = 0; c < nchunks; ++c) {
    ((float4*)sh)[tid] = v;
    __syncthreads();
    if (c + 1 < nchunks) v = gbase[(c + 1) * 256 + tid];  // prefetch next chunk
#pragma unroll
    for (int k = 0; k < 8; ++k) {
      float av[8], bv[8];
      *(float4*)&av[0] = *(const float4*)&sh[k * DD + a0];
      *(float4*)&av[4] = *(const float4*)&sh[k * DD + a0 + 4];
      *(float4*)&bv[0] = *(const float4*)&sh[k * DD + b0];
      *(float4*)&bv[4] = *(const float4*)&sh[k * DD + b0 + 4];
#pragma unroll
      for (int i = 0; i < 8; ++i)
#pragma unroll
        for (int j = 0; j < 8; ++j)
          acc[i][j] = fmaf(av[i], bv[j], acc[i][j]);
    }
    __syncthreads();
  }

  // write private partial tile (no atomics)
  float* __restrict__ dst = (isX ? apart : bpart) + (size_t)p * (DD * DD);
#pragma unroll
  for (int i = 0; i < 8; ++i) {
    *(float4*)&dst[(a0 + i) * DD + b0]     = *(const float4*)&acc[i][0];
    *(float4*)&dst[(a0 + i) * DD + b0 + 4] = *(const float4*)&acc[i][4];
  }

  if (isX) {
    // diag partials over rows [row0, row0+slab): 32 lanes x float4 per row
    const int lane = tid & 31;
    const int rg = tid >> 5;  // 8 row-groups
    double s1 = 0.0, s2 = 0.0;
    for (int r = rg; r < slab; r += 8) {
      const int row = row0 + r;
      float4 xv = ((const float4*)(x + (size_t)row * DD))[lane];
      float4 yv = ((const float4*)(y + (size_t)row * DD))[lane];
      float d = xv.x * yv.x + xv.y * yv.y + xv.z * yv.z + xv.w * yv.w;
#pragma unroll
      for (int off = 16; off > 0; off >>= 1)
        d += __shfl_down(d, off, 32);
      if (lane == 0) { s1 += (double)d; s2 += (double)d * (double)d; }
    }
    if (lane == 0) {
      atomicAdd(&sc[0], s1);
      atomicAdd(&sc[1], s2);
    }
  }
}

// ---------------------------------------------------------------------------
// Stage 2: S = sum_ab (sum_p apart[p]) * (sum_p bpart[p]).
// 64 blocks x 256 threads; each thread owns one of the 16384 (a,b) entries.
// Coalesced: consecutive threads read consecutive entries within each partial.
// ---------------------------------------------------------------------------
__global__ __launch_bounds__(256)
void dot_kernel(const float* __restrict__ apart, const float* __restrict__ bpart,
                double* __restrict__ sc, int P)
{
  const int e = blockIdx.x * 256 + threadIdx.x;  // [0, 16384)
  float sa = 0.f, sb = 0.f;
  for (int p = 0; p < P; ++p) {
    sa += apart[(size_t)p * (DD * DD) + e];
    sb += bpart[(size_t)p * (DD * DD) + e];
  }
  double prod = (double)sa * (double)sb;
#pragma unroll
  for (int off = 32; off > 0; off >>= 1)
    prod += __shfl_down(prod, off, 64);
  __shared__ double wsum[4];
  const int lane = threadIdx.x & 63, w = threadIdx.x >> 6;
  if (lane == 0) wsum[w] = prod;
  __syncthreads();
  if (threadIdx.x == 0) {
    double t = wsum[0] + wsum[1] + wsum[2] + wsum[3];
    atomicAdd(&sc[2], t);
  }
}

// ---------------------------------------------------------------------------
// Stage 3: combine into the scalar loss.
// loss = (S - s2)/(N(N-1)) - (2/N) * s1
// ---------------------------------------------------------------------------
__global__ void finish_kernel(const double* __restrict__ sc,
                              float* __restrict__ out, int N)
{
  double s1 = sc[0], s2 = sc[1], S = sc[2];
  double loss = (S - s2) / ((double)N * (double)(N - 1)) - (2.0 / N) * s1;
  out[0] = (float)loss;
}

extern "C" void kernel_launch(void* const* d_in, const int* in_sizes, int n_in,
                              void* d_out, int out_size, void* d_ws, size_t ws_size,
                              hipStream_t stream) {
  const float* x = (const float*)d_in[0];
  const float* y = (const float*)d_in[1];
  float* out = (float*)d_out;
  const int N = in_sizes[0] / DD;  // 8192

  // P partial tiles per matrix; storage = 2*P*128*128*4 B. Prefer P=128
  // (16 MB, 256 blocks -> 1 block/CU full utilization); shrink if ws small.
  int P = 128;
  while (P > 8 && (size_t)2 * P * DD * DD * sizeof(float) + 64 > ws_size) P >>= 1;

  float* apart = (float*)d_ws;
  float* bpart = apart + (size_t)P * DD * DD;
  double* sc = (double*)((char*)d_ws + (size_t)2 * P * DD * DD * sizeof(float));

  hipMemsetAsync(sc, 0, 3 * sizeof(double), stream);
  gram_kernel<<<2 * P, 256, 0, stream>>>(x, y, apart, bpart, sc, N, P);
  dot_kernel<<<(DD * DD) / 256, 256, 0, stream>>>(apart, bpart, sc, P);
  finish_kernel<<<1, 1, 0, stream>>>(sc, out, N);
}

// Round 2
// 94.793 us; speedup vs baseline: 1.3104x; 1.3104x over previous
//
#include <hip/hip_runtime.h>

#define DD 128  // feature dim

// ---------------------------------------------------------------------------
// Stage 1: per-block partial Gram tiles  A = X^T X, B = Y^T Y  (each 128x128).
// Grid = 2*P blocks: [0,P) -> X slab -> apart[p], [P,2P) -> Y slab -> bpart[p].
// Block = 256 threads as 16x16; each thread owns an 8x8 tile (64 fp32 acc in
// VGPRs). Rows staged through LDS in 8-row chunks with register prefetch.
// X-blocks ALSO compute the diagonal sums s1 = sum <x_i,y_i>,
// s2 = sum <x_i,y_i>^2 inline: the y float4 matching each staged x float4 is
// loaded alongside and reduced with 32-wide shuffles while in registers.
// ---------------------------------------------------------------------------
__global__ __launch_bounds__(256)
void gram_kernel(const float* __restrict__ x, const float* __restrict__ y,
                 float* __restrict__ apart, float* __restrict__ bpart,
                 double* __restrict__ sc, int N, int P)
{
  const int blk = blockIdx.x;
  const bool isX = blk < P;
  const int p = isX ? blk : blk - P;
  const float* __restrict__ src = isX ? x : y;
  const int slab = N / P;
  const int row0 = p * slab;

  __shared__ float sh[8 * DD];     // 8 rows x 128 floats = 4 KB
  __shared__ double dred[8][2];    // per-row-group diag partials

  const int tid = threadIdx.x;
  const int tx = tid & 15, ty = tid >> 4;
  const int a0 = ty * 8, b0 = tx * 8;

  float acc[8][8];
#pragma unroll
  for (int i = 0; i < 8; ++i)
#pragma unroll
    for (int j = 0; j < 8; ++j) acc[i][j] = 0.f;

  const float4* gbase = (const float4*)(src + (size_t)row0 * DD);
  const float4* ybase = (const float4*)(y + (size_t)row0 * DD);
  const int nchunks = slab / 8;  // chunk = 8 rows = 256 float4
  double s1 = 0.0, s2 = 0.0;

  float4 v = gbase[tid];
  float4 w;
  if (isX) w = ybase[tid];

  for (int c = 0; c < nchunks; ++c) {
    ((float4*)sh)[tid] = v;
    if (isX) {
      // diag contribution for this chunk while v,w are live in registers:
      // thread tid holds floats [(tid&31)*4 .. +3] of row (tid>>5).
      float d = v.x * w.x + v.y * w.y + v.z * w.z + v.w * w.w;
#pragma unroll
      for (int off = 16; off > 0; off >>= 1)
        d += __shfl_down(d, off, 32);
      if ((tid & 31) == 0) { s1 += (double)d; s2 += (double)d * (double)d; }
    }
    __syncthreads();
    if (c + 1 < nchunks) {
      v = gbase[(c + 1) * 256 + tid];       // prefetch next chunk
      if (isX) w = ybase[(c + 1) * 256 + tid];
    }
#pragma unroll
    for (int k = 0; k < 8; ++k) {
      float av[8], bv[8];
      *(float4*)&av[0] = *(const float4*)&sh[k * DD + a0];
      *(float4*)&av[4] = *(const float4*)&sh[k * DD + a0 + 4];
      *(float4*)&bv[0] = *(const float4*)&sh[k * DD + b0];
      *(float4*)&bv[4] = *(const float4*)&sh[k * DD + b0 + 4];
#pragma unroll
      for (int i = 0; i < 8; ++i)
#pragma unroll
        for (int j = 0; j < 8; ++j)
          acc[i][j] = fmaf(av[i], bv[j], acc[i][j]);
    }
    __syncthreads();
  }

  // write private partial tile (no atomics)
  float* __restrict__ dst = (isX ? apart : bpart) + (size_t)p * (DD * DD);
#pragma unroll
  for (int i = 0; i < 8; ++i) {
    *(float4*)&dst[(a0 + i) * DD + b0]     = *(const float4*)&acc[i][0];
    *(float4*)&dst[(a0 + i) * DD + b0 + 4] = *(const float4*)&acc[i][4];
  }

  if (isX) {
    if ((tid & 31) == 0) { dred[tid >> 5][0] = s1; dred[tid >> 5][1] = s2; }
    __syncthreads();
    if (tid == 0) {
      double t1 = 0.0, t2 = 0.0;
#pragma unroll
      for (int g = 0; g < 8; ++g) { t1 += dred[g][0]; t2 += dred[g][1]; }
      atomicAdd(&sc[0], t1);
      atomicAdd(&sc[1], t2);
    }
  }
}

// ---------------------------------------------------------------------------
// Stage 2 (+finish): S = sum_ab (sum_p apart[p])_ab * (sum_p bpart[p])_ab.
// 256 blocks x 64 threads (1 wave each, all CUs pulling BW); thread owns one
// (a,b) entry. Last block (device-scope ticket) computes the final loss:
//   loss = (S - s2)/(N(N-1)) - (2/N)*s1
// ---------------------------------------------------------------------------
__global__ __launch_bounds__(64)
void dot_kernel(const float* __restrict__ apart, const float* __restrict__ bpart,
                double* __restrict__ sc, unsigned int* __restrict__ cnt,
                float* __restrict__ out, int N, int P, int nblocks)
{
  const int e = blockIdx.x * 64 + threadIdx.x;  // [0, 16384)
  float sa = 0.f, sb = 0.f;
#pragma unroll 8
  for (int p = 0; p < P; ++p) {
    sa += apart[(size_t)p * (DD * DD) + e];
    sb += bpart[(size_t)p * (DD * DD) + e];
  }
  double prod = (double)sa * (double)sb;
#pragma unroll
  for (int off = 32; off > 0; off >>= 1)
    prod += __shfl_down(prod, off, 64);

  if (threadIdx.x == 0) {
    atomicAdd(&sc[2], prod);
    __threadfence();
    unsigned int old = atomicAdd(cnt, 1u);
    if (old == (unsigned int)(nblocks - 1)) {
      // last block: all sc[2] contributions are globally visible.
      double s1 = atomicAdd(&sc[0], 0.0);  // coherent read-backs
      double s2 = atomicAdd(&sc[1], 0.0);
      double S  = atomicAdd(&sc[2], 0.0);
      double loss = (S - s2) / ((double)N * (double)(N - 1)) - (2.0 / N) * s1;
      out[0] = (float)loss;
    }
  }
}

extern "C" void kernel_launch(void* const* d_in, const int* in_sizes, int n_in,
                              void* d_out, int out_size, void* d_ws, size_t ws_size,
                              hipStream_t stream) {
  const float* x = (const float*)d_in[0];
  const float* y = (const float*)d_in[1];
  float* out = (float*)d_out;
  const int N = in_sizes[0] / DD;  // 8192

  int P = 128;  // 256 gram blocks, 16 MB of partials
  while (P > 8 && (size_t)2 * P * DD * DD * sizeof(float) + 64 > ws_size) P >>= 1;

  float* apart = (float*)d_ws;
  float* bpart = apart + (size_t)P * DD * DD;
  double* sc = (double*)((char*)d_ws + (size_t)2 * P * DD * DD * sizeof(float));
  unsigned int* cnt = (unsigned int*)(sc + 3);

  hipMemsetAsync(sc, 0, 3 * sizeof(double) + sizeof(unsigned int), stream);
  gram_kernel<<<2 * P, 256, 0, stream>>>(x, y, apart, bpart, sc, N, P);
  const int nblocks = (DD * DD) / 64;  // 256
  dot_kernel<<<nblocks, 64, 0, stream>>>(apart, bpart, sc, cnt, out, N, P, nblocks);
}

// Round 3
// 87.670 us; speedup vs baseline: 1.4169x; 1.0812x over previous
//
#include <hip/hip_runtime.h>

#define DD 128  // feature dim

// ---------------------------------------------------------------------------
// Stage 1: per-block partial Gram tiles  A = X^T X, B = Y^T Y  (each 128x128).
// Grid = 2*P blocks: [0,P) -> X slab -> apart[p], [P,2P) -> Y slab -> bpart[p].
// Block = 512 threads = TWO 256-thread teams splitting the slab's k-chunks
// (team t handles chunks c ≡ t mod 2), giving 8 waves/block = 2 waves/SIMD
// for latency hiding. Each team: 16x16 thread grid, 8x8 fp32 acc tile per
// thread, own 4 KB LDS staging buffer (barriers align across teams).
// Epilogue: team 1 parks its acc in a 64 KB LDS tile; team 0 adds and writes.
// X-blocks also fold in diag sums s1 = sum <x_i,y_i>, s2 = sum <x_i,y_i>^2
// from the staged registers (32-wide shuffle reduce).
// ---------------------------------------------------------------------------
__global__ __launch_bounds__(512)
void gram_kernel(const float* __restrict__ x, const float* __restrict__ y,
                 float* __restrict__ apart, float* __restrict__ bpart,
                 double* __restrict__ sc, int N, int P)
{
  const int blk = blockIdx.x;
  const bool isX = blk < P;
  const int p = isX ? blk : blk - P;
  const float* __restrict__ src = isX ? x : y;
  const int slab = N / P;        // 64 rows
  const int row0 = p * slab;

  __shared__ float sh[2][8 * DD];   // per-team 8-row staging (2 x 4 KB)
  __shared__ float comb[DD * DD];   // 64 KB team-combine tile
  __shared__ double dred[16][2];    // per-32-lane-group diag partials

  const int tid = threadIdx.x;
  const int team = tid >> 8;        // 0 or 1
  const int t = tid & 255;
  const int tx = t & 15, ty = t >> 4;
  const int a0 = ty * 8, b0 = tx * 8;

  float acc[8][8];
#pragma unroll
  for (int i = 0; i < 8; ++i)
#pragma unroll
    for (int j = 0; j < 8; ++j) acc[i][j] = 0.f;

  const float4* gbase = (const float4*)(src + (size_t)row0 * DD);
  const float4* ybase = (const float4*)(y + (size_t)row0 * DD);
  const int nchunks = slab / 8;     // 8 chunks; team does nchunks/2
  double s1 = 0.0, s2 = 0.0;

  // chunk indices for this team: team, team+2, ...
  float4 v = gbase[team * 256 + t];
  float4 w;
  if (isX) w = ybase[team * 256 + t];

  for (int c = team; c < nchunks; c += 2) {
    ((float4*)sh[team])[t] = v;
    if (isX) {
      // thread t holds floats [(t&31)*4 .. +3] of row (t>>3... group t>>5)
      float d = v.x * w.x + v.y * w.y + v.z * w.z + v.w * w.w;
#pragma unroll
      for (int off = 16; off > 0; off >>= 1)
        d += __shfl_down(d, off, 32);
      if ((t & 31) == 0) { s1 += (double)d; s2 += (double)d * (double)d; }
    }
    __syncthreads();
    if (c + 2 < nchunks) {
      v = gbase[(c + 2) * 256 + t];          // prefetch team's next chunk
      if (isX) w = ybase[(c + 2) * 256 + t];
    }
    const float* shb = sh[team];
#pragma unroll
    for (int k = 0; k < 8; ++k) {
      float av[8], bv[8];
      *(float4*)&av[0] = *(const float4*)&shb[k * DD + a0];
      *(float4*)&av[4] = *(const float4*)&shb[k * DD + a0 + 4];
      *(float4*)&bv[0] = *(const float4*)&shb[k * DD + b0];
      *(float4*)&bv[4] = *(const float4*)&shb[k * DD + b0 + 4];
#pragma unroll
      for (int i = 0; i < 8; ++i)
#pragma unroll
        for (int j = 0; j < 8; ++j)
          acc[i][j] = fmaf(av[i], bv[j], acc[i][j]);
    }
    __syncthreads();
  }

  // ---- epilogue: diag partials + team combine ----
  if (isX && (t & 31) == 0) {
    dred[tid >> 5][0] = s1;
    dred[tid >> 5][1] = s2;
  }
  if (team == 1) {
#pragma unroll
    for (int i = 0; i < 8; ++i) {
      *(float4*)&comb[(a0 + i) * DD + b0]     = *(const float4*)&acc[i][0];
      *(float4*)&comb[(a0 + i) * DD + b0 + 4] = *(const float4*)&acc[i][4];
    }
  }
  __syncthreads();

  if (team == 0) {
    float* __restrict__ dst = (isX ? apart : bpart) + (size_t)p * (DD * DD);
#pragma unroll
    for (int i = 0; i < 8; ++i) {
#pragma unroll
      for (int j = 0; j < 8; ++j)
        acc[i][j] += comb[(a0 + i) * DD + b0 + j];
      *(float4*)&dst[(a0 + i) * DD + b0]     = *(const float4*)&acc[i][0];
      *(float4*)&dst[(a0 + i) * DD + b0 + 4] = *(const float4*)&acc[i][4];
    }
  }

  if (isX && tid == 0) {
    double t1 = 0.0, t2 = 0.0;
#pragma unroll
    for (int g = 0; g < 16; ++g) { t1 += dred[g][0]; t2 += dred[g][1]; }
    atomicAdd(&sc[0], t1);
    atomicAdd(&sc[1], t2);
  }
}

// ---------------------------------------------------------------------------
// Stage 2 (+finish): S = sum_ab (sum_p apart[p])_ab * (sum_p bpart[p])_ab.
// 256 blocks x 256 threads; block owns 64 (a,b) entries; wave w sums partials
// p ≡ w (mod 4) (coalesced 256 B lines), LDS cross-wave combine, 64-wide
// shuffle reduce, one double atomic per block. Last block (device ticket)
// computes loss = (S - s2)/(N(N-1)) - (2/N)*s1.
// ---------------------------------------------------------------------------
__global__ __launch_bounds__(256)
void dot_kernel(const float* __restrict__ apart, const float* __restrict__ bpart,
                double* __restrict__ sc, unsigned int* __restrict__ cnt,
                float* __restrict__ out, int N, int P, int nblocks)
{
  const int w = threadIdx.x >> 6, lane = threadIdx.x & 63;
  const int e = blockIdx.x * 64 + lane;  // [0, 16384)
  float sa = 0.f, sb = 0.f;
#pragma unroll 8
  for (int p = w; p < P; p += 4) {
    sa += apart[(size_t)p * (DD * DD) + e];
    sb += bpart[(size_t)p * (DD * DD) + e];
  }
  __shared__ float sA[4][64], sB[4][64];
  sA[w][lane] = sa;
  sB[w][lane] = sb;
  __syncthreads();
  if (w == 0) {
    float ta = sA[0][lane] + sA[1][lane] + sA[2][lane] + sA[3][lane];
    float tb = sB[0][lane] + sB[1][lane] + sB[2][lane] + sB[3][lane];
    double prod = (double)ta * (double)tb;
#pragma unroll
    for (int off = 32; off > 0; off >>= 1)
      prod += __shfl_down(prod, off, 64);
    if (lane == 0) {
      atomicAdd(&sc[2], prod);
      __threadfence();
      unsigned int old = atomicAdd(cnt, 1u);
      if (old == (unsigned int)(nblocks - 1)) {
        double s1 = atomicAdd(&sc[0], 0.0);
        double s2 = atomicAdd(&sc[1], 0.0);
        double S  = atomicAdd(&sc[2], 0.0);
        double loss = (S - s2) / ((double)N * (double)(N - 1)) - (2.0 / N) * s1;
        out[0] = (float)loss;
      }
    }
  }
}

extern "C" void kernel_launch(void* const* d_in, const int* in_sizes, int n_in,
                              void* d_out, int out_size, void* d_ws, size_t ws_size,
                              hipStream_t stream) {
  const float* x = (const float*)d_in[0];
  const float* y = (const float*)d_in[1];
  float* out = (float*)d_out;
  const int N = in_sizes[0] / DD;  // 8192

  int P = 128;  // 256 gram blocks (1/CU, 8 waves each), 16 MB of partials
  while (P > 8 && (size_t)2 * P * DD * DD * sizeof(float) + 64 > ws_size) P >>= 1;

  float* apart = (float*)d_ws;
  float* bpart = apart + (size_t)P * DD * DD;
  double* sc = (double*)((char*)d_ws + (size_t)2 * P * DD * DD * sizeof(float));
  unsigned int* cnt = (unsigned int*)(sc + 3);

  hipMemsetAsync(sc, 0, 3 * sizeof(double) + sizeof(unsigned int), stream);
  gram_kernel<<<2 * P, 512, 0, stream>>>(x, y, apart, bpart, sc, N, P);
  const int nblocks = (DD * DD) / 64;  // 256
  dot_kernel<<<nblocks, 256, 0, stream>>>(apart, bpart, sc, cnt, out, N, P, nblocks);
}

// Round 4
// 83.153 us; speedup vs baseline: 1.4939x; 1.0543x over previous
//
#include <hip/hip_runtime.h>

#define DD 128  // feature dim
#define SR 72   // LDS row stride in bf16 units (64 + 8 pad -> 144 B, bank-spread)

typedef float f32x4 __attribute__((ext_vector_type(4)));
typedef short s16x8 __attribute__((ext_vector_type(8)));

// ---------------------------------------------------------------------------
// Stage 1: per-block partial Gram tiles A = X^T X, B = Y^T Y via MFMA.
// Grid = 2*P blocks of 512 threads (8 waves). Block p handles a 64-row slab.
// fp32 is split into bf16 hi (truncation) + bf16 lo (residual); the slab is
// staged TRANSPOSED in LDS as Xt[feat][k] so both A- and B-fragments of the
// symmetric product are contiguous 16 B reads:
//   A-frag: A[m=lane&15][k=(lane>>4)*8+j] = Xt[m0+lane&15][k...]
//   B-frag: B[k][n=lane&15]               = Xt[n0+lane&15][k...]
// G = Xh^T Xh + Xh^T Xl + Xl^T Xh (ll term dropped, ~2^-15 relative).
// Wave w owns tile-row w (8 tiles of 16x16, acc = 8 x f32x4 = 32 VGPRs).
// C/D layout (m89-verified): col = lane&15, row = (lane>>4)*4 + reg.
// X-blocks also fold diag sums s1=sum<x_i,y_i>, s2=sum<...>^2 from the
// ORIGINAL fp32 loads (8-lane shuffle per row, then wave/block reduce).
// ---------------------------------------------------------------------------
__global__ __launch_bounds__(512)
void gram_kernel(const float* __restrict__ x, const float* __restrict__ y,
                 float* __restrict__ apart, float* __restrict__ bpart,
                 double* __restrict__ sc, int N, int P)
{
  const int blk = blockIdx.x;
  const bool isX = blk < P;
  const int p = isX ? blk : blk - P;
  const float* __restrict__ src = isX ? x : y;
  const int slab = N / P;        // multiple of 64
  const int row0 = p * slab;

  __shared__ __align__(16) unsigned short sh_hi[DD * SR];  // 18.4 KB
  __shared__ __align__(16) unsigned short sh_lo[DD * SR];  // 18.4 KB
  __shared__ double wred[8][2];

  const int tid = threadIdx.x;
  const int wave = tid >> 6, lane = tid & 63;
  const int rloc = tid >> 3;     // row within 64-row chunk
  const int f = tid & 3 ? tid & 7 : tid & 7;  // float4 group 0..7
  const int fg = tid & 7;

  f32x4 acc[8];
#pragma unroll
  for (int t = 0; t < 8; ++t)
#pragma unroll
    for (int k = 0; k < 4; ++k) acc[t][k] = 0.f;

  double s1 = 0.0, s2 = 0.0;
  const int nch = slab >> 6;

  for (int c = 0; c < nch; ++c) {
    const float* cb = src + (size_t)(row0 + (c << 6)) * DD;
    const float4* rowp = (const float4*)(cb + rloc * DD);
    float4 v0 = rowp[fg], v1 = rowp[fg + 8], v2 = rowp[fg + 16], v3 = rowp[fg + 24];

    if (isX) {
      const float4* yrp = (const float4*)(y + (size_t)(row0 + (c << 6)) * DD + rloc * DD);
      float4 w0 = yrp[fg], w1 = yrp[fg + 8], w2 = yrp[fg + 16], w3 = yrp[fg + 24];
      float d = v0.x*w0.x + v0.y*w0.y + v0.z*w0.z + v0.w*w0.w
              + v1.x*w1.x + v1.y*w1.y + v1.z*w1.z + v1.w*w1.w
              + v2.x*w2.x + v2.y*w2.y + v2.z*w2.z + v2.w*w2.w
              + v3.x*w3.x + v3.y*w3.y + v3.z*w3.z + v3.w*w3.w;
      d += __shfl_down(d, 4, 8);
      d += __shfl_down(d, 2, 8);
      d += __shfl_down(d, 1, 8);
      if (fg == 0) { s1 += (double)d; s2 += (double)d * (double)d; }
    }

    __syncthreads();  // previous chunk's fragment reads done before overwrite
    {
      float vals[16] = {v0.x, v0.y, v0.z, v0.w, v1.x, v1.y, v1.z, v1.w,
                        v2.x, v2.y, v2.z, v2.w, v3.x, v3.y, v3.z, v3.w};
#pragma unroll
      for (int j = 0; j < 4; ++j)
#pragma unroll
        for (int cc = 0; cc < 4; ++cc) {
          const int m = ((fg + (j << 3)) << 2) + cc;
          const float vv = vals[j * 4 + cc];
          const unsigned int b = __float_as_uint(vv);
          const unsigned short hb = (unsigned short)(b >> 16);
          const float hf = __uint_as_float(b & 0xffff0000u);
          const float lf = vv - hf;
          const unsigned short lb = (unsigned short)(__float_as_uint(lf) >> 16);
          sh_hi[m * SR + rloc] = hb;
          sh_lo[m * SR + rloc] = lb;
        }
    }
    __syncthreads();

#pragma unroll
    for (int kb = 0; kb < 64; kb += 32) {
      const int ko = kb + ((lane >> 4) << 3);
      const int arow = (wave * 16 + (lane & 15)) * SR + ko;
      const s16x8 ahi = *(const s16x8*)&sh_hi[arow];
      const s16x8 alo = *(const s16x8*)&sh_lo[arow];
#pragma unroll
      for (int t = 0; t < 8; ++t) {
        const int brow = (t * 16 + (lane & 15)) * SR + ko;
        const s16x8 bhi = *(const s16x8*)&sh_hi[brow];
        const s16x8 blo = *(const s16x8*)&sh_lo[brow];
        acc[t] = __builtin_amdgcn_mfma_f32_16x16x32_bf16(ahi, bhi, acc[t], 0, 0, 0);
        acc[t] = __builtin_amdgcn_mfma_f32_16x16x32_bf16(ahi, blo, acc[t], 0, 0, 0);
        acc[t] = __builtin_amdgcn_mfma_f32_16x16x32_bf16(alo, bhi, acc[t], 0, 0, 0);
      }
    }
  }

  // write private partial tile
  float* __restrict__ dst = (isX ? apart : bpart) + (size_t)p * (DD * DD);
  const int col = lane & 15;
  const int rb = (lane >> 4) << 2;
#pragma unroll
  for (int t = 0; t < 8; ++t)
#pragma unroll
    for (int rg = 0; rg < 4; ++rg)
      dst[(wave * 16 + rb + rg) * DD + t * 16 + col] = acc[t][rg];

  if (isX) {
    // partials live on lanes 0,8,...,56 of each wave
    s1 += __shfl_down(s1, 32, 64); s2 += __shfl_down(s2, 32, 64);
    s1 += __shfl_down(s1, 16, 64); s2 += __shfl_down(s2, 16, 64);
    s1 += __shfl_down(s1, 8, 64);  s2 += __shfl_down(s2, 8, 64);
    if (lane == 0) { wred[wave][0] = s1; wred[wave][1] = s2; }
    __syncthreads();
    if (tid == 0) {
      double t1 = 0.0, t2 = 0.0;
#pragma unroll
      for (int g = 0; g < 8; ++g) { t1 += wred[g][0]; t2 += wred[g][1]; }
      atomicAdd(&sc[0], t1);
      atomicAdd(&sc[1], t2);
    }
  }
}

// ---------------------------------------------------------------------------
// Stage 2 (+finish): S = sum_ab (sum_p apart[p])_ab * (sum_p bpart[p])_ab.
// 256 blocks x 256 threads; block owns 64 (a,b) entries; wave w sums partials
// p ≡ w (mod 4), LDS cross-wave combine, 64-wide shuffle reduce, one double
// atomic per block. Last block (device ticket) computes
//   loss = (S - s2)/(N(N-1)) - (2/N)*s1.
// ---------------------------------------------------------------------------
__global__ __launch_bounds__(256)
void dot_kernel(const float* __restrict__ apart, const float* __restrict__ bpart,
                double* __restrict__ sc, unsigned int* __restrict__ cnt,
                float* __restrict__ out, int N, int P, int nblocks)
{
  const int w = threadIdx.x >> 6, lane = threadIdx.x & 63;
  const int e = blockIdx.x * 64 + lane;  // [0, 16384)
  float sa = 0.f, sb = 0.f;
#pragma unroll 8
  for (int p = w; p < P; p += 4) {
    sa += apart[(size_t)p * (DD * DD) + e];
    sb += bpart[(size_t)p * (DD * DD) + e];
  }
  __shared__ float sA[4][64], sB[4][64];
  sA[w][lane] = sa;
  sB[w][lane] = sb;
  __syncthreads();
  if (w == 0) {
    float ta = sA[0][lane] + sA[1][lane] + sA[2][lane] + sA[3][lane];
    float tb = sB[0][lane] + sB[1][lane] + sB[2][lane] + sB[3][lane];
    double prod = (double)ta * (double)tb;
#pragma unroll
    for (int off = 32; off > 0; off >>= 1)
      prod += __shfl_down(prod, off, 64);
    if (lane == 0) {
      atomicAdd(&sc[2], prod);
      __threadfence();
      unsigned int old = atomicAdd(cnt, 1u);
      if (old == (unsigned int)(nblocks - 1)) {
        double s1 = atomicAdd(&sc[0], 0.0);
        double s2 = atomicAdd(&sc[1], 0.0);
        double S  = atomicAdd(&sc[2], 0.0);
        double loss = (S - s2) / ((double)N * (double)(N - 1)) - (2.0 / N) * s1;
        out[0] = (float)loss;
      }
    }
  }
}

extern "C" void kernel_launch(void* const* d_in, const int* in_sizes, int n_in,
                              void* d_out, int out_size, void* d_ws, size_t ws_size,
                              hipStream_t stream) {
  const float* x = (const float*)d_in[0];
  const float* y = (const float*)d_in[1];
  float* out = (float*)d_out;
  const int N = in_sizes[0] / DD;  // 8192

  int P = 128;  // 256 gram blocks (1/CU, 8 waves each), 16 MB of partials
  while (P > 8 && (size_t)2 * P * DD * DD * sizeof(float) + 64 > ws_size) P >>= 1;

  float* apart = (float*)d_ws;
  float* bpart = apart + (size_t)P * DD * DD;
  double* sc = (double*)((char*)d_ws + (size_t)2 * P * DD * DD * sizeof(float));
  unsigned int* cnt = (unsigned int*)(sc + 3);

  hipMemsetAsync(sc, 0, 3 * sizeof(double) + sizeof(unsigned int), stream);
  gram_kernel<<<2 * P, 512, 0, stream>>>(x, y, apart, bpart, sc, N, P);
  const int nblocks = (DD * DD) / 64;  // 256
  dot_kernel<<<nblocks, 256, 0, stream>>>(apart, bpart, sc, cnt, out, N, P, nblocks);
}

// Round 7
// 75.503 us; speedup vs baseline: 1.6452x; 1.1013x over previous
//
#include <hip/hip_runtime.h>

#define DD 128   // feature dim
#define SR 72    // LDS row stride in bf16 units (64 + 8 pad, bank-spread)
#define PP 128   // partial tiles per matrix
#define NB (2*PP)

typedef float f32x4 __attribute__((ext_vector_type(4)));
typedef short s16x8 __attribute__((ext_vector_type(8)));

// ---------------------------------------------------------------------------
// Dispatch 1: per-block partial Gram tiles A_p = Xslab^T Xslab (blk<PP) or
// B_p = Yslab^T Yslab via bf16 hi/lo-split MFMA (G = Xh'Xh + Xh'Xl + Xl'Xh,
// ll dropped, ~2^-15 relative). 64-row slab staged TRANSPOSED in LDS
// (Xt[feat][k], 16 B-contiguous in k for both A- and B-fragments; layout
// m89-verified: C/D col = lane&15, row = (lane>>4)*4 + reg).
// X-blocks fold diag sums s1 = sum<x_i,y_i>, s2 = sum<..>^2 from the
// original fp32 registers -> PLAIN stores into per-block slots (no memset).
// Block 0 also zeroes the dispatch-2 ticket counter (stream-order visible).
// NO grid-wide sync anywhere (R5/R6 post-mortem: spin barriers deadlock,
// cooperative launch breaks graph capture).
// ---------------------------------------------------------------------------
__global__ __launch_bounds__(512)
void gram_kernel(const float* __restrict__ x, const float* __restrict__ y,
                 float* __restrict__ apart, float* __restrict__ bpart,
                 double* __restrict__ ds1, double* __restrict__ ds2,
                 unsigned int* __restrict__ cnt, int N)
{
  const int blk = blockIdx.x;
  const bool isX = blk < PP;
  const int p = isX ? blk : blk - PP;
  const float* __restrict__ src = isX ? x : y;
  const int slab = N / PP;       // 64
  const int row0 = p * slab;

  if (blk == 0 && threadIdx.x == 0) *cnt = 0;  // ticket init for dispatch 2

  __shared__ __align__(16) unsigned short sh_hi[DD * SR];  // 18.4 KB
  __shared__ __align__(16) unsigned short sh_lo[DD * SR];  // 18.4 KB
  __shared__ double wred[8][2];

  const int tid = threadIdx.x;
  const int wave = tid >> 6, lane = tid & 63;
  const int rloc = tid >> 3;     // row within 64-row chunk
  const int fg = tid & 7;        // float4 group within row

  f32x4 acc[8];
#pragma unroll
  for (int t = 0; t < 8; ++t)
#pragma unroll
    for (int k = 0; k < 4; ++k) acc[t][k] = 0.f;

  double s1 = 0.0, s2 = 0.0;

  {
    const float* cb = src + (size_t)row0 * DD;
    const float4* rowp = (const float4*)(cb + rloc * DD);
    float4 v0 = rowp[fg], v1 = rowp[fg + 8], v2 = rowp[fg + 16], v3 = rowp[fg + 24];

    if (isX) {
      const float4* yrp = (const float4*)(y + (size_t)row0 * DD + rloc * DD);
      float4 w0 = yrp[fg], w1 = yrp[fg + 8], w2 = yrp[fg + 16], w3 = yrp[fg + 24];
      float d = v0.x*w0.x + v0.y*w0.y + v0.z*w0.z + v0.w*w0.w
              + v1.x*w1.x + v1.y*w1.y + v1.z*w1.z + v1.w*w1.w
              + v2.x*w2.x + v2.y*w2.y + v2.z*w2.z + v2.w*w2.w
              + v3.x*w3.x + v3.y*w3.y + v3.z*w3.z + v3.w*w3.w;
      d += __shfl_down(d, 4, 8);
      d += __shfl_down(d, 2, 8);
      d += __shfl_down(d, 1, 8);
      if (fg == 0) { s1 += (double)d; s2 += (double)d * (double)d; }
    }

    {
      float vals[16] = {v0.x, v0.y, v0.z, v0.w, v1.x, v1.y, v1.z, v1.w,
                        v2.x, v2.y, v2.z, v2.w, v3.x, v3.y, v3.z, v3.w};
#pragma unroll
      for (int j = 0; j < 4; ++j)
#pragma unroll
        for (int cc = 0; cc < 4; ++cc) {
          const int m = ((fg + (j << 3)) << 2) + cc;
          const float vv = vals[j * 4 + cc];
          const unsigned int b = __float_as_uint(vv);
          const unsigned short hb = (unsigned short)(b >> 16);
          const float hf = __uint_as_float(b & 0xffff0000u);
          const float lf = vv - hf;
          const unsigned short lb = (unsigned short)(__float_as_uint(lf) >> 16);
          sh_hi[m * SR + rloc] = hb;
          sh_lo[m * SR + rloc] = lb;
        }
    }
    __syncthreads();

#pragma unroll
    for (int kb = 0; kb < 64; kb += 32) {
      const int ko = kb + ((lane >> 4) << 3);
      const int arow = (wave * 16 + (lane & 15)) * SR + ko;
      const s16x8 ahi = *(const s16x8*)&sh_hi[arow];
      const s16x8 alo = *(const s16x8*)&sh_lo[arow];
#pragma unroll
      for (int t = 0; t < 8; ++t) {
        const int brow = (t * 16 + (lane & 15)) * SR + ko;
        const s16x8 bhi = *(const s16x8*)&sh_hi[brow];
        const s16x8 blo = *(const s16x8*)&sh_lo[brow];
        acc[t] = __builtin_amdgcn_mfma_f32_16x16x32_bf16(ahi, bhi, acc[t], 0, 0, 0);
        acc[t] = __builtin_amdgcn_mfma_f32_16x16x32_bf16(ahi, blo, acc[t], 0, 0, 0);
        acc[t] = __builtin_amdgcn_mfma_f32_16x16x32_bf16(alo, bhi, acc[t], 0, 0, 0);
      }
    }
  }

  // write private partial tile (C/D layout: col = lane&15, row = (lane>>4)*4+reg)
  float* __restrict__ dst = (isX ? apart : bpart) + (size_t)p * (DD * DD);
  const int col = lane & 15;
  const int rb = (lane >> 4) << 2;
#pragma unroll
  for (int t = 0; t < 8; ++t)
#pragma unroll
    for (int rg = 0; rg < 4; ++rg)
      dst[(wave * 16 + rb + rg) * DD + t * 16 + col] = acc[t][rg];

  if (isX) {
    // diag partials live on lanes 0,8,...,56 of each wave
    s1 += __shfl_down(s1, 32, 64); s2 += __shfl_down(s2, 32, 64);
    s1 += __shfl_down(s1, 16, 64); s2 += __shfl_down(s2, 16, 64);
    s1 += __shfl_down(s1, 8, 64);  s2 += __shfl_down(s2, 8, 64);
    if (lane == 0) { wred[wave][0] = s1; wred[wave][1] = s2; }
    __syncthreads();
    if (tid == 0) {
      double t1 = 0.0, t2 = 0.0;
#pragma unroll
      for (int g = 0; g < 8; ++g) { t1 += wred[g][0]; t2 += wred[g][1]; }
      ds1[p] = t1;   // plain stores, no init required
      ds2[p] = t2;
    }
  }
}

// ---------------------------------------------------------------------------
// Dispatch 2 (+finish): S = sum_ab (sum_p A_p)_ab * (sum_p B_p)_ab.
// 256 blocks x 256 threads; block owns 64 (a,b) entries; wave w sums partials
// p ≡ w (mod 4), LDS combine, 64-wide shuffle reduce -> prod[blk] plain
// store. Ticket (counter zeroed by dispatch 1): last block reduces the 256
// prods + 128 diag slots in double and writes the scalar loss.
// ---------------------------------------------------------------------------
__global__ __launch_bounds__(256)
void dot_kernel(const float* __restrict__ apart, const float* __restrict__ bpart,
                const double* __restrict__ ds1, const double* __restrict__ ds2,
                double* __restrict__ prod, unsigned int* __restrict__ cnt,
                float* __restrict__ out, int N, int nblocks)
{
  const int w = threadIdx.x >> 6, lane = threadIdx.x & 63;
  const int tid = threadIdx.x;
  const int e = blockIdx.x * 64 + lane;  // [0, 16384)
  float sa = 0.f, sb = 0.f;
#pragma unroll 8
  for (int p = w; p < PP; p += 4) {
    sa += apart[(size_t)p * (DD * DD) + e];
    sb += bpart[(size_t)p * (DD * DD) + e];
  }
  __shared__ float sA[4][64], sB[4][64];
  __shared__ int amLast;
  sA[w][lane] = sa;
  sB[w][lane] = sb;
  __syncthreads();
  if (tid == 0) {
    float ta = 0.f, tb = 0.f;
    // lane-0 only needs its own column combined below via shuffle path; do
    // the cross-wave combine for all 64 entries in wave 0 instead:
    amLast = 0;
  }
  if (w == 0) {
    float ta = sA[0][lane] + sA[1][lane] + sA[2][lane] + sA[3][lane];
    float tb = sB[0][lane] + sB[1][lane] + sB[2][lane] + sB[3][lane];
    double pr = (double)ta * (double)tb;
#pragma unroll
    for (int off = 32; off > 0; off >>= 1)
      pr += __shfl_down(pr, off, 64);
    if (lane == 0) {
      prod[blockIdx.x] = pr;        // plain store
      __threadfence();              // make prod visible before ticket
      unsigned int old = atomicAdd(cnt, 1u);
      if (old == (unsigned int)(nblocks - 1)) amLast = 1;
    }
  }
  __syncthreads();
  if (amLast && tid < 64) {
    __threadfence();  // acquire side: all other blocks' prod stores visible
    double S  = prod[tid] + prod[tid + 64] + prod[tid + 128] + prod[tid + 192];
    double t1 = ds1[tid] + ds1[tid + 64];
    double t2 = ds2[tid] + ds2[tid + 64];
#pragma unroll
    for (int off = 32; off > 0; off >>= 1) {
      S  += __shfl_down(S, off, 64);
      t1 += __shfl_down(t1, off, 64);
      t2 += __shfl_down(t2, off, 64);
    }
    if (tid == 0) {
      double loss = (S - t2) / ((double)N * (double)(N - 1)) - (2.0 / N) * t1;
      out[0] = (float)loss;
    }
  }
}

extern "C" void kernel_launch(void* const* d_in, const int* in_sizes, int n_in,
                              void* d_out, int out_size, void* d_ws, size_t ws_size,
                              hipStream_t stream) {
  const float* x = (const float*)d_in[0];
  const float* y = (const float*)d_in[1];
  float* out = (float*)d_out;
  const int N = in_sizes[0] / DD;  // 8192

  char* w = (char*)d_ws;
  float* apart = (float*)w;                              w += (size_t)PP * DD * DD * 4;
  float* bpart = (float*)w;                              w += (size_t)PP * DD * DD * 4;
  double* ds1  = (double*)w;                             w += PP * 8;
  double* ds2  = (double*)w;                             w += PP * 8;
  double* prod = (double*)w;                             w += NB * 8;
  unsigned int* cnt = (unsigned int*)w;

  gram_kernel<<<NB, 512, 0, stream>>>(x, y, apart, bpart, ds1, ds2, cnt, N);
  const int nblocks = (DD * DD) / 64;  // 256
  dot_kernel<<<nblocks, 256, 0, stream>>>(apart, bpart, ds1, ds2, prod, cnt,
                                          out, N, nblocks);
}